// Round 3
// baseline (1361.505 us; speedup 1.0000x reference)
//
#include <hip/hip_runtime.h>

#define V 30000
#define E 100
#define H 100
#define T 9
#define B 256
#define S 512

typedef float v2f __attribute__((ext_vector_type(2)));

__device__ __forceinline__ float fast_rcp(float x) { return __builtin_amdgcn_rcpf(x); }

template <int PAT>
__device__ __forceinline__ float dpp_mov(float x) {
  int t = __builtin_amdgcn_update_dpp(0, __builtin_bit_cast(int, x), PAT, 0xF, 0xF, true);
  return __builtin_bit_cast(float, t);
}

__device__ __forceinline__ float read_lane(float x, int lane) {
  return __builtin_bit_cast(float, __builtin_amdgcn_readlane(__builtin_bit_cast(int, x), lane));
}

// ---------------------------------------------------------------------------
// Kernel 1: P_d = embed @ Wih_d^T + b_d, PERMUTED columns:
//   P'[v][4*j + q] = P[v][q*100 + j]  (q = gate, j = unit)
// o-tiles live in PERM space (coalesced float4 stores); W tile (64 cols x
// 100 k) staged transposed in LDS (LDW=66 -> 2-way write conflict = free,
// b64 reads); embed kept OUT of LDS: per-thread 8 vocab rows via float4
// global loads (16 lanes share each address -> broadcast coalesce).
// Per-thread tile 8v x 4o -> 64 pk-FMA per k-chunk vs 8 LDS b64 reads.
// ---------------------------------------------------------------------------
#define BV 128
#define BO 64
#define LDW 66

__global__ __launch_bounds__(256) void precompute_P(
    const float* __restrict__ embed,
    const float* __restrict__ Wih_f, const float* __restrict__ b_f,
    const float* __restrict__ Wih_b, const float* __restrict__ b_b,
    float* __restrict__ Pf, float* __restrict__ Pb)
{
  __shared__ __align__(16) float wT[100 * LDW];
  __shared__ __align__(16) float bT[BO];
  int tid = threadIdx.x;
  int p0 = blockIdx.x * BO;   // perm-space column base [0, 832)
  int v0 = blockIdx.y * BV;

  // stage W transposed, perm-space columns: wT[k*LDW + pi] = Wrow(invperm(p0+pi))[k]
  for (int idx = tid; idx < BO * 100; idx += 256) {
    int k = idx % 100, pi = idx / 100;
    int p = p0 + pi;
    float val = 0.0f;
    if (p < 800) {
      int pd = (p < 400) ? p : (p - 400);
      int oo = (pd & 3) * 100 + (pd >> 2);   // invperm
      val = (p < 400) ? Wih_f[oo * E + k] : Wih_b[oo * E + k];
    }
    wT[k * LDW + pi] = val;
  }
  if (tid < BO) {
    int p = p0 + tid;
    float val = 0.0f;
    if (p < 800) {
      int pd = (p < 400) ? p : (p - 400);
      int oo = (pd & 3) * 100 + (pd >> 2);
      val = (p < 400) ? b_f[oo] : b_b[oo];
    }
    bT[tid] = val;
  }
  __syncthreads();

  int tx = tid & 15, ty = tid >> 4;
  int pi0 = tx * 4;          // 4 perm-cols per thread
  int vi0 = ty * 8;          // 8 vocab rows per thread

  const float4* rp[8];
#pragma unroll
  for (int j = 0; j < 8; j++) {
    int v = v0 + vi0 + j;
    if (v > V - 1) v = V - 1;          // clamp; store guarded below
    rp[j] = (const float4*)(embed + (size_t)v * E);
  }

  v2f acc[8][2];
#pragma unroll
  for (int j = 0; j < 8; j++) { acc[j][0] = (v2f){0.f, 0.f}; acc[j][1] = (v2f){0.f, 0.f}; }

  for (int kc = 0; kc < 25; kc++) {
    float er[8][4];
#pragma unroll
    for (int j = 0; j < 8; j++) {
      float4 t4 = rp[j][kc];
      er[j][0] = t4.x; er[j][1] = t4.y; er[j][2] = t4.z; er[j][3] = t4.w;
    }
#pragma unroll
    for (int kk = 0; kk < 4; kk++) {
      const float* wrow = &wT[(kc * 4 + kk) * LDW + pi0];
      v2f w01 = *(const v2f*)&wrow[0];
      v2f w23 = *(const v2f*)&wrow[2];
#pragma unroll
      for (int j = 0; j < 8; j++) {
        v2f es = {er[j][kk], er[j][kk]};
        acc[j][0] = __builtin_elementwise_fma(es, w01, acc[j][0]);
        acc[j][1] = __builtin_elementwise_fma(es, w23, acc[j][1]);
      }
    }
  }

  int p = p0 + pi0;
  if (p < 800) {
    v2f b01 = *(const v2f*)&bT[pi0];
    v2f b23 = *(const v2f*)&bT[pi0 + 2];
    float* dst;
    int col;
    if (p < 400) { dst = Pf; col = p; } else { dst = Pb; col = p - 400; }
#pragma unroll
    for (int j = 0; j < 8; j++) {
      int v = v0 + vi0 + j;
      if (v < V) {
        float4 o4 = { acc[j][0].x + b01.x, acc[j][0].y + b01.y,
                      acc[j][1].x + b23.x, acc[j][1].y + b23.y };
        *(float4*)&dst[(size_t)v * 400 + col] = o4;
      }
    }
  }
}

// ---------------------------------------------------------------------------
// Kernel 2: LSTM recurrence. One (dir,row) chain per block; 512 blocks,
// block = 512 threads (8 waves), 2 blocks/CU.
//   tid<400: og=tid>>2 (unit), kq=tid&3 (K-quarter). Packed v_pk_fma, DPP
//     quad reduce-scatter -> own-gate activation -> quad broadcasts -> c/h.
//     P row read from LDS ring (one conflict-free ds_read_b32).
//   tid>=448 (wave 7): P-row prefetch DEPTH-2 into 4-buffer P_lds ring
//     (load issued 2 steps ahead -> >= 1 full step of VMEM latency budget),
//     plus em tag projection on lanes 448..484.
// ONE barrier per step.
// ---------------------------------------------------------------------------
__global__ __attribute__((amdgpu_flat_work_group_size(512, 512), amdgpu_waves_per_eu(4, 4)))
void lstm_kernel(
    const int* __restrict__ x,
    const float* __restrict__ Pf, const float* __restrict__ Pb,
    const float* __restrict__ Whh_f, const float* __restrict__ Whh_b,
    const float* __restrict__ Wlin,
    float* __restrict__ em_f, float* __restrict__ em_b)
{
  __shared__ __align__(16) float h_lds[2][104];
  __shared__ __align__(16) float P_lds[4][400];
  __shared__ int   x_lds[S];
  __shared__ float em_lds[S * T];

  int tid = threadIdx.x;
  int dir = blockIdx.x & 1;
  int b   = blockIdx.x >> 1;

  const float* P   = dir ? Pb : Pf;
  const float* Whh = dir ? Whh_b : Whh_f;
  float*       em  = dir ? em_b : em_f;

  bool is_mv = (tid < 400);
  int  og = tid >> 2, kq = tid & 3;
  bool lo2  = (kq < 2);
  bool oddl = (kq & 1);

  bool is_pf = (tid >= 448);               // wave 7: prefetch + em
  int  pl = tid - 448;
  bool is_em = (tid >= 448 && tid < 448 + 4 * T);
  int  et = tid - 448;
  int  etag = et >> 2, ekq = et & 3;

  // hoisted own-gate activation constants (gate 2 = tanh, others = sigmoid)
  float mexp = (kq == 2) ? -2.f : -1.f;
  float sA   = (kq == 2) ?  2.f :  1.f;
  float sB   = (kq == 2) ? -1.f :  0.f;

  // weights: 4 gates x (24 quarter + 1 remainder) = 100 floats
  v2f  w2[4][12];
  float wr[4];
  if (is_mv) {
#pragma unroll
    for (int q = 0; q < 4; q++) {
      const float* row = &Whh[(size_t)(q * 100 + og) * 100];
#pragma unroll
      for (int i = 0; i < 6; i++) {
        float4 t4 = *(const float4*)&row[24 * kq + 4 * i];
        w2[q][2 * i]     = (v2f){t4.x, t4.y};
        w2[q][2 * i + 1] = (v2f){t4.z, t4.w};
      }
      wr[q] = row[96 + kq];
    }
  } else if (is_em) {
    const float* row = &Wlin[etag * (2 * H) + dir * H];
#pragma unroll
    for (int i = 0; i < 6; i++) {
      float4 t4 = *(const float4*)&row[24 * ekq + 4 * i];
      w2[0][2 * i]     = (v2f){t4.x, t4.y};
      w2[0][2 * i + 1] = (v2f){t4.z, t4.w};
    }
    wr[0] = row[96 + ekq];
  }

  for (int i = tid; i < 208; i += 512) ((float*)h_lds)[i] = 0.f;
  for (int i = tid; i < S; i += 512) x_lds[i] = x[(size_t)b * S + i];
  float c = 0.f;
  // preload P rows for steps 0 and 1 into ring buffers 0,1
  if (is_pf) {
#pragma unroll
    for (int s0 = 0; s0 < 2; s0++) {
      int tts = dir ? (S - 1 - s0) : s0;
      const float* rowp = P + (size_t)x[(size_t)b * S + tts] * 400;
      for (int i = pl; i < 400; i += 64) P_lds[s0][i] = rowp[i];
    }
  }
  int prev_tt = 0;
  __syncthreads();

  auto step = [&](int bufc, int t) {
    int tt = dir ? (S - 1 - t) : t;
    if (is_mv) {
      float prv = P_lds[t & 3][tid];        // conflict-free, prefetched 2 steps ago
      const float* hq = &h_lds[bufc][24 * kq];
      v2f a0 = {0.f, 0.f}, a1 = {0.f, 0.f}, a2 = {0.f, 0.f}, a3 = {0.f, 0.f};
#pragma unroll
      for (int i = 0; i < 6; i++) {
        float4 h4 = *(const float4*)&hq[4 * i];
        v2f hlo = {h4.x, h4.y}, hhi = {h4.z, h4.w};
        a0 = __builtin_elementwise_fma(w2[0][2 * i], hlo, a0);
        a0 = __builtin_elementwise_fma(w2[0][2 * i + 1], hhi, a0);
        a1 = __builtin_elementwise_fma(w2[1][2 * i], hlo, a1);
        a1 = __builtin_elementwise_fma(w2[1][2 * i + 1], hhi, a1);
        a2 = __builtin_elementwise_fma(w2[2][2 * i], hlo, a2);
        a2 = __builtin_elementwise_fma(w2[2][2 * i + 1], hhi, a2);
        a3 = __builtin_elementwise_fma(w2[3][2 * i], hlo, a3);
        a3 = __builtin_elementwise_fma(w2[3][2 * i + 1], hhi, a3);
      }
      float hr = h_lds[bufc][96 + kq];
      float p0 = fmaf(wr[0], hr, a0.x + a0.y);
      float p1 = fmaf(wr[1], hr, a1.x + a1.y);
      float p2 = fmaf(wr[2], hr, a2.x + a2.y);
      float p3 = fmaf(wr[3], hr, a3.x + a3.y);

      // DPP quad reduce-scatter: lane kq ends with full sum of gate kq
      float u  = lo2 ? p2 : p0;
      float v  = lo2 ? p3 : p1;
      float ru = dpp_mov<0x4E>(u);          // quad_perm [2,3,0,1]
      float rv = dpp_mov<0x4E>(v);
      float A  = (lo2 ? p0 : p2) + ru;
      float Bv = (lo2 ? p1 : p3) + rv;
      float wv = oddl ? A : Bv;
      float rw = dpp_mov<0xB1>(wv);         // quad_perm [1,0,3,2]
      float g  = (oddl ? Bv : A) + rw + prv;

      // own-gate activation
      float e   = __expf(mexp * g);
      float act = fmaf(sA, fast_rcp(1.f + e), sB);

      // broadcast each quad lane's activation
      float gi = dpp_mov<0x00>(act);
      float gf = dpp_mov<0x55>(act);
      float tg = dpp_mov<0xAA>(act);
      float go = dpp_mov<0xFF>(act);

      c = fmaf(gf, c, gi * tg);
      float th = fmaf(2.f, fast_rcp(1.f + __expf(-2.f * c)), -1.f);
      if (kq == 0) h_lds[bufc ^ 1][og] = go * th;
    } else if (is_pf) {
      // depth-2 prefetch: load P row for step t+2 into ring buffer (t+2)&3
      if (t + 2 < S) {
        int ttn = dir ? (S - 3 - t) : (t + 2);
        int xv = x_lds[ttn];                // wave-uniform
        unsigned sxv = __builtin_amdgcn_readfirstlane(xv);
        const float* rowp = P + (size_t)sxv * 400;
        float* dstp = P_lds[(t + 2) & 3];
#pragma unroll
        for (int u = 0; u < 7; u++) {
          int idx = pl + 64 * u;
          if (idx < 400) dstp[idx] = rowp[idx];
        }
      }
      if (is_em && t > 0) {
        const float* hq = &h_lds[bufc][24 * ekq];
        v2f a = {0.f, 0.f};
#pragma unroll
        for (int i = 0; i < 6; i++) {
          float4 h4 = *(const float4*)&hq[4 * i];
          a = __builtin_elementwise_fma(w2[0][2 * i], (v2f){h4.x, h4.y}, a);
          a = __builtin_elementwise_fma(w2[0][2 * i + 1], (v2f){h4.z, h4.w}, a);
        }
        float hr = h_lds[bufc][96 + ekq];
        float p = fmaf(wr[0], hr, a.x + a.y);
        p += dpp_mov<0xB1>(p);
        p += dpp_mov<0x4E>(p);
        if (ekq == 0) em_lds[prev_tt * T + etag] = p;
      }
    }
    __syncthreads();
    prev_tt = tt;
  };

  for (int t = 0; t < S; t += 2) {
    step(0, t);
    step(1, t + 1);
  }

  if (is_em) {   // final step's projection (h(S-1) in h_lds[0])
    const float* hq = &h_lds[0][24 * ekq];
    v2f a = {0.f, 0.f};
#pragma unroll
    for (int i = 0; i < 6; i++) {
      float4 h4 = *(const float4*)&hq[4 * i];
      a = __builtin_elementwise_fma(w2[0][2 * i], (v2f){h4.x, h4.y}, a);
      a = __builtin_elementwise_fma(w2[0][2 * i + 1], (v2f){h4.z, h4.w}, a);
    }
    float hr = h_lds[0][96 + ekq];
    float p = fmaf(wr[0], hr, a.x + a.y);
    p += dpp_mov<0xB1>(p);
    p += dpp_mov<0x4E>(p);
    if (ekq == 0) em_lds[prev_tt * T + etag] = p;
  }
  __syncthreads();

  float* dst = em + (size_t)b * S * T;
  for (int i = tid; i < S * T; i += 512) dst[i] = em_lds[i];
}

// ---------------------------------------------------------------------------
// Kernel 3: Viterbi. DP without __shfl: broadcast the 9 scores via
// v_readlane (no LDS-pipe round trip), value max-tree + first-match argmax
// (identical tie-break to jnp.argmax), ev[t+1] prefetched one step ahead.
// bp stride 16. One wave per row.
// ---------------------------------------------------------------------------
__global__ __launch_bounds__(64) void viterbi_kernel(
    const float* __restrict__ em_f, const float* __restrict__ em_b,
    const float* __restrict__ blin, const float* __restrict__ start,
    const float* __restrict__ trans, const float* __restrict__ endv,
    float* __restrict__ out)
{
  __shared__ float ev[S * 12];         // 24.6 KB combined emissions
  __shared__ unsigned char bp[S * 16]; // 8 KB backpointers (stride 16)
  int b = blockIdx.x;
  int lane = threadIdx.x;
  bool act = (lane < T);
  int tag = act ? lane : 0;

  const float* ef = em_f + (size_t)b * S * T;
  const float* eb = em_b + (size_t)b * S * T;
  for (int i = lane; i < S * T; i += 64) {
    int t = i / 9, tg = i - t * 9;
    ev[t * 12 + tg] = ef[i] + eb[i] + blin[tg];
  }
  __syncthreads();

  float tc[T] = {};
  float en = 0.f;
  float score = -1e30f;
  if (act) {
#pragma unroll
    for (int p = 0; p < T; p++) tc[p] = trans[p * T + tag];
    en = endv[tag];
    score = start[tag] + ev[tag];
  }

  float evn = ev[12 + tag];            // prefetch ev for t=1
  for (int t = 1; t < S; t++) {
    float evcur = evn;
    if (t + 1 < S) evn = ev[(t + 1) * 12 + tag];   // prefetch next (off dep path)
    float cand[T];
#pragma unroll
    for (int p = 0; p < T; p++) cand[p] = read_lane(score, p) + tc[p];
    float best = cand[0];
#pragma unroll
    for (int p = 1; p < T; p++) best = fmaxf(best, cand[p]);
    int bestp = T - 1;
#pragma unroll
    for (int p = T - 2; p >= 0; p--) bestp = (cand[p] == best) ? p : bestp;  // first max
    if (act) {
      score = best + evcur;
      bp[t * 16 + tag] = (unsigned char)bestp;
    }
  }
  if (act) score += en;
  __syncthreads();

  float cf[T];
#pragma unroll
  for (int p = 0; p < T; p++) cf[p] = read_lane(score, p);
  float bs = cf[0];
#pragma unroll
  for (int p = 1; p < T; p++) bs = fmaxf(bs, cf[p]);
  int last = T - 1;
#pragma unroll
  for (int p = T - 2; p >= 0; p--) last = (cf[p] == bs) ? p : last;

  if (lane == 0) {
    out[(size_t)B * S + b] = bs;
    int cur = last;
    out[(size_t)b * S + (S - 1)] = (float)cur;
    for (int t = S - 1; t >= 1; t--) {
      cur = bp[t * 16 + cur];
      out[(size_t)b * S + (t - 1)] = (float)cur;
    }
  }
}

// ---------------------------------------------------------------------------
extern "C" void kernel_launch(void* const* d_in, const int* in_sizes, int n_in,
                              void* d_out, int out_size, void* d_ws, size_t ws_size,
                              hipStream_t stream)
{
  const int*   x     = (const int*)d_in[0];
  const float* embed = (const float*)d_in[2];
  const float* Wih_f = (const float*)d_in[3];
  const float* Whh_f = (const float*)d_in[4];
  const float* b_f   = (const float*)d_in[5];
  const float* Wih_b = (const float*)d_in[6];
  const float* Whh_b = (const float*)d_in[7];
  const float* b_b   = (const float*)d_in[8];
  const float* Wlin  = (const float*)d_in[9];
  const float* blin  = (const float*)d_in[10];
  const float* start = (const float*)d_in[11];
  const float* trans = (const float*)d_in[12];
  const float* endv  = (const float*)d_in[13];
  float* out = (float*)d_out;

  char* ws = (char*)d_ws;
  float* Pf   = (float*)ws;  ws += (size_t)V * 400 * sizeof(float);
  float* Pb   = (float*)ws;  ws += (size_t)V * 400 * sizeof(float);
  float* emf  = (float*)ws;  ws += (size_t)B * S * T * sizeof(float);
  float* emb_ = (float*)ws;  ws += (size_t)B * S * T * sizeof(float);

  precompute_P<<<dim3(13, 235), 256, 0, stream>>>(embed, Wih_f, b_f, Wih_b, b_b, Pf, Pb);
  lstm_kernel<<<dim3(512), 512, 0, stream>>>(x, Pf, Pb, Whh_f, Whh_b, Wlin, emf, emb_);
  viterbi_kernel<<<dim3(256), 64, 0, stream>>>(emf, emb_, blin, start, trans, endv, out);
}

// Round 4
// 739.422 us; speedup vs baseline: 1.8413x; 1.8413x over previous
//
#include <hip/hip_runtime.h>

#define V 30000
#define E 100
#define H 100
#define T 9
#define B 256
#define S 512

typedef float v2f __attribute__((ext_vector_type(2)));

__device__ __forceinline__ float fast_rcp(float x) { return __builtin_amdgcn_rcpf(x); }

template <int PAT>
__device__ __forceinline__ float dpp_mov(float x) {
  int t = __builtin_amdgcn_update_dpp(0, __builtin_bit_cast(int, x), PAT, 0xF, 0xF, true);
  return __builtin_bit_cast(float, t);
}

__device__ __forceinline__ float read_lane(float x, int lane) {
  return __builtin_bit_cast(float, __builtin_amdgcn_readlane(__builtin_bit_cast(int, x), lane));
}

// ---------------------------------------------------------------------------
// Kernel 1: P_d = embed @ Wih_d^T + b_d, PERMUTED columns:
//   P'[v][4*j + q] = P[v][q*100 + j]  (q = gate, j = unit)
// o-tiles live in PERM space (coalesced float4 stores); W tile (64 cols x
// 100 k) staged transposed in LDS (LDW=66 -> 2-way write conflict = free,
// b64 reads); embed kept OUT of LDS: per-thread 8 vocab rows via float4
// global loads (16 lanes share each address -> broadcast coalesce).
// ---------------------------------------------------------------------------
#define BV 128
#define BO 64
#define LDW 66

__global__ __launch_bounds__(256) void precompute_P(
    const float* __restrict__ embed,
    const float* __restrict__ Wih_f, const float* __restrict__ b_f,
    const float* __restrict__ Wih_b, const float* __restrict__ b_b,
    float* __restrict__ Pf, float* __restrict__ Pb)
{
  __shared__ __align__(16) float wT[100 * LDW];
  __shared__ __align__(16) float bT[BO];
  int tid = threadIdx.x;
  int p0 = blockIdx.x * BO;   // perm-space column base [0, 832)
  int v0 = blockIdx.y * BV;

  // stage W transposed, perm-space columns: wT[k*LDW + pi] = Wrow(invperm(p0+pi))[k]
  for (int idx = tid; idx < BO * 100; idx += 256) {
    int k = idx % 100, pi = idx / 100;
    int p = p0 + pi;
    float val = 0.0f;
    if (p < 800) {
      int pd = (p < 400) ? p : (p - 400);
      int oo = (pd & 3) * 100 + (pd >> 2);   // invperm
      val = (p < 400) ? Wih_f[oo * E + k] : Wih_b[oo * E + k];
    }
    wT[k * LDW + pi] = val;
  }
  if (tid < BO) {
    int p = p0 + tid;
    float val = 0.0f;
    if (p < 800) {
      int pd = (p < 400) ? p : (p - 400);
      int oo = (pd & 3) * 100 + (pd >> 2);
      val = (p < 400) ? b_f[oo] : b_b[oo];
    }
    bT[tid] = val;
  }
  __syncthreads();

  int tx = tid & 15, ty = tid >> 4;
  int pi0 = tx * 4;          // 4 perm-cols per thread
  int vi0 = ty * 8;          // 8 vocab rows per thread

  const float4* rp[8];
#pragma unroll
  for (int j = 0; j < 8; j++) {
    int v = v0 + vi0 + j;
    if (v > V - 1) v = V - 1;          // clamp; store guarded below
    rp[j] = (const float4*)(embed + (size_t)v * E);
  }

  v2f acc[8][2];
#pragma unroll
  for (int j = 0; j < 8; j++) { acc[j][0] = (v2f){0.f, 0.f}; acc[j][1] = (v2f){0.f, 0.f}; }

  for (int kc = 0; kc < 25; kc++) {
    float er[8][4];
#pragma unroll
    for (int j = 0; j < 8; j++) {
      float4 t4 = rp[j][kc];
      er[j][0] = t4.x; er[j][1] = t4.y; er[j][2] = t4.z; er[j][3] = t4.w;
    }
#pragma unroll
    for (int kk = 0; kk < 4; kk++) {
      const float* wrow = &wT[(kc * 4 + kk) * LDW + pi0];
      v2f w01 = *(const v2f*)&wrow[0];
      v2f w23 = *(const v2f*)&wrow[2];
#pragma unroll
      for (int j = 0; j < 8; j++) {
        v2f es = {er[j][kk], er[j][kk]};
        acc[j][0] = __builtin_elementwise_fma(es, w01, acc[j][0]);
        acc[j][1] = __builtin_elementwise_fma(es, w23, acc[j][1]);
      }
    }
  }

  int p = p0 + pi0;
  if (p < 800) {
    v2f b01 = *(const v2f*)&bT[pi0];
    v2f b23 = *(const v2f*)&bT[pi0 + 2];
    float* dst;
    int col;
    if (p < 400) { dst = Pf; col = p; } else { dst = Pb; col = p - 400; }
#pragma unroll
    for (int j = 0; j < 8; j++) {
      int v = v0 + vi0 + j;
      if (v < V) {
        float4 o4 = { acc[j][0].x + b01.x, acc[j][0].y + b01.y,
                      acc[j][1].x + b23.x, acc[j][1].y + b23.y };
        *(float4*)&dst[(size_t)v * 400 + col] = o4;
      }
    }
  }
}

// ---------------------------------------------------------------------------
// Kernel 2: LSTM recurrence (round-0 register-prefetch design, 520 µs
// verified). One (dir,row) chain per block; 512 blocks, 512 threads.
//   tid<400: og=tid>>2 (unit), kq=tid&3 (K-quarter). Packed v_pk_fma, DPP
//     quad reduce-scatter -> own-gate activation -> quad broadcasts -> c/h.
//     P-row prefetch ONE STEP AHEAD into a register: x via LDS, row base
//     via readfirstlane (SALU math, single saddr+voffset global load) --
//     VMEM latency hides under the current step's FMA work, waitcnt lands
//     at next step's use. Do NOT route P through LDS: a same-phase
//     load->waitcnt->ds_write on one wave exposes the full round-trip at
//     the barrier (measured: 520 -> 1111 µs regression).
//   tid in [448,484): em tag projection (quad all-reduce).
// ONE barrier per step.
// ---------------------------------------------------------------------------
__global__ __attribute__((amdgpu_flat_work_group_size(512, 512), amdgpu_waves_per_eu(4, 4)))
void lstm_kernel(
    const int* __restrict__ x,
    const float* __restrict__ Pf, const float* __restrict__ Pb,
    const float* __restrict__ Whh_f, const float* __restrict__ Whh_b,
    const float* __restrict__ Wlin,
    float* __restrict__ em_f, float* __restrict__ em_b)
{
  __shared__ __align__(16) float h_lds[2][104];
  __shared__ int   x_lds[S];
  __shared__ float em_lds[S * T];

  int tid = threadIdx.x;
  int dir = blockIdx.x & 1;
  int b   = blockIdx.x >> 1;

  const float* P   = dir ? Pb : Pf;
  const float* Whh = dir ? Whh_b : Whh_f;
  float*       em  = dir ? em_b : em_f;

  bool is_mv = (tid < 400);
  int  og = tid >> 2, kq = tid & 3;
  bool lo2  = (kq < 2);
  bool oddl = (kq & 1);

  bool is_em = (tid >= 448 && tid < 448 + 4 * T);
  int  et = tid - 448;
  int  etag = et >> 2, ekq = et & 3;

  // hoisted own-gate activation constants (gate 2 = tanh, others = sigmoid)
  float mexp = (kq == 2) ? -2.f : -1.f;
  float sA   = (kq == 2) ?  2.f :  1.f;
  float sB   = (kq == 2) ? -1.f :  0.f;

  // weights: 4 gates x (24 quarter + 1 remainder) = 100 floats
  v2f  w2[4][12];
  float wr[4];
  if (is_mv) {
#pragma unroll
    for (int q = 0; q < 4; q++) {
      const float* row = &Whh[(size_t)(q * 100 + og) * 100];
#pragma unroll
      for (int i = 0; i < 6; i++) {
        float4 t4 = *(const float4*)&row[24 * kq + 4 * i];
        w2[q][2 * i]     = (v2f){t4.x, t4.y};
        w2[q][2 * i + 1] = (v2f){t4.z, t4.w};
      }
      wr[q] = row[96 + kq];
    }
  } else if (is_em) {
    const float* row = &Wlin[etag * (2 * H) + dir * H];
#pragma unroll
    for (int i = 0; i < 6; i++) {
      float4 t4 = *(const float4*)&row[24 * ekq + 4 * i];
      w2[0][2 * i]     = (v2f){t4.x, t4.y};
      w2[0][2 * i + 1] = (v2f){t4.z, t4.w};
    }
    wr[0] = row[96 + ekq];
  }

  for (int i = tid; i < 208; i += 512) ((float*)h_lds)[i] = 0.f;
  for (int i = tid; i < S; i += 512) x_lds[i] = x[(size_t)b * S + i];
  float c = 0.f;
  float pre = 0.f;
  if (is_mv) {
    int tt0 = dir ? (S - 1) : 0;
    pre = P[(size_t)x[(size_t)b * S + tt0] * 400 + tid];
  }
  int prev_tt = 0;
  __syncthreads();

  auto step = [&](int bufc, int t) {
    int tt = dir ? (S - 1 - t) : t;
    if (is_mv) {
      float prv = pre;
      if (t + 1 < S) {                      // register prefetch, SGPR base
        int ttn = dir ? (S - 2 - t) : (t + 1);
        int xv = x_lds[ttn];                // wave-uniform
        unsigned sxv = __builtin_amdgcn_readfirstlane(xv);
        const float* rowp = P + (size_t)sxv * 400;
        pre = rowp[tid];
      }
      const float* hq = &h_lds[bufc][24 * kq];
      v2f a0 = {0.f, 0.f}, a1 = {0.f, 0.f}, a2 = {0.f, 0.f}, a3 = {0.f, 0.f};
#pragma unroll
      for (int i = 0; i < 6; i++) {
        float4 h4 = *(const float4*)&hq[4 * i];
        v2f hlo = {h4.x, h4.y}, hhi = {h4.z, h4.w};
        a0 = __builtin_elementwise_fma(w2[0][2 * i], hlo, a0);
        a0 = __builtin_elementwise_fma(w2[0][2 * i + 1], hhi, a0);
        a1 = __builtin_elementwise_fma(w2[1][2 * i], hlo, a1);
        a1 = __builtin_elementwise_fma(w2[1][2 * i + 1], hhi, a1);
        a2 = __builtin_elementwise_fma(w2[2][2 * i], hlo, a2);
        a2 = __builtin_elementwise_fma(w2[2][2 * i + 1], hhi, a2);
        a3 = __builtin_elementwise_fma(w2[3][2 * i], hlo, a3);
        a3 = __builtin_elementwise_fma(w2[3][2 * i + 1], hhi, a3);
      }
      float hr = h_lds[bufc][96 + kq];
      float p0 = fmaf(wr[0], hr, a0.x + a0.y);
      float p1 = fmaf(wr[1], hr, a1.x + a1.y);
      float p2 = fmaf(wr[2], hr, a2.x + a2.y);
      float p3 = fmaf(wr[3], hr, a3.x + a3.y);

      // DPP quad reduce-scatter: lane kq ends with full sum of gate kq
      float u  = lo2 ? p2 : p0;
      float v  = lo2 ? p3 : p1;
      float ru = dpp_mov<0x4E>(u);          // quad_perm [2,3,0,1]
      float rv = dpp_mov<0x4E>(v);
      float A  = (lo2 ? p0 : p2) + ru;
      float Bv = (lo2 ? p1 : p3) + rv;
      float wv = oddl ? A : Bv;
      float rw = dpp_mov<0xB1>(wv);         // quad_perm [1,0,3,2]
      float g  = (oddl ? Bv : A) + rw + prv;

      // own-gate activation
      float e   = __expf(mexp * g);
      float act = fmaf(sA, fast_rcp(1.f + e), sB);

      // broadcast each quad lane's activation
      float gi = dpp_mov<0x00>(act);
      float gf = dpp_mov<0x55>(act);
      float tg = dpp_mov<0xAA>(act);
      float go = dpp_mov<0xFF>(act);

      c = fmaf(gf, c, gi * tg);
      float th = fmaf(2.f, fast_rcp(1.f + __expf(-2.f * c)), -1.f);
      if (kq == 0) h_lds[bufc ^ 1][og] = go * th;
    } else if (is_em && t > 0) {
      const float* hq = &h_lds[bufc][24 * ekq];
      v2f a = {0.f, 0.f};
#pragma unroll
      for (int i = 0; i < 6; i++) {
        float4 h4 = *(const float4*)&hq[4 * i];
        a = __builtin_elementwise_fma(w2[0][2 * i], (v2f){h4.x, h4.y}, a);
        a = __builtin_elementwise_fma(w2[0][2 * i + 1], (v2f){h4.z, h4.w}, a);
      }
      float hr = h_lds[bufc][96 + ekq];
      float p = fmaf(wr[0], hr, a.x + a.y);
      p += dpp_mov<0xB1>(p);
      p += dpp_mov<0x4E>(p);
      if (ekq == 0) em_lds[prev_tt * T + etag] = p;
    }
    __syncthreads();
    prev_tt = tt;
  };

  for (int t = 0; t < S; t += 2) {
    step(0, t);
    step(1, t + 1);
  }

  if (is_em) {   // final step's projection (h(S-1) in h_lds[0])
    const float* hq = &h_lds[0][24 * ekq];
    v2f a = {0.f, 0.f};
#pragma unroll
    for (int i = 0; i < 6; i++) {
      float4 h4 = *(const float4*)&hq[4 * i];
      a = __builtin_elementwise_fma(w2[0][2 * i], (v2f){h4.x, h4.y}, a);
      a = __builtin_elementwise_fma(w2[0][2 * i + 1], (v2f){h4.z, h4.w}, a);
    }
    float hr = h_lds[0][96 + ekq];
    float p = fmaf(wr[0], hr, a.x + a.y);
    p += dpp_mov<0xB1>(p);
    p += dpp_mov<0x4E>(p);
    if (ekq == 0) em_lds[prev_tt * T + etag] = p;
  }
  __syncthreads();

  float* dst = em + (size_t)b * S * T;
  for (int i = tid; i < S * T; i += 512) dst[i] = em_lds[i];
}

// ---------------------------------------------------------------------------
// Kernel 3: Viterbi. DP without __shfl: broadcast the 9 scores via
// v_readlane (no LDS-pipe round trip), value max-tree + first-match argmax
// (identical tie-break to jnp.argmax), ev[t+1] prefetched one step ahead.
// bp stride 16. One wave per row.
// ---------------------------------------------------------------------------
__global__ __launch_bounds__(64) void viterbi_kernel(
    const float* __restrict__ em_f, const float* __restrict__ em_b,
    const float* __restrict__ blin, const float* __restrict__ start,
    const float* __restrict__ trans, const float* __restrict__ endv,
    float* __restrict__ out)
{
  __shared__ float ev[S * 12];         // 24.6 KB combined emissions
  __shared__ unsigned char bp[S * 16]; // 8 KB backpointers (stride 16)
  int b = blockIdx.x;
  int lane = threadIdx.x;
  bool act = (lane < T);
  int tag = act ? lane : 0;

  const float* ef = em_f + (size_t)b * S * T;
  const float* eb = em_b + (size_t)b * S * T;
  for (int i = lane; i < S * T; i += 64) {
    int t = i / 9, tg = i - t * 9;
    ev[t * 12 + tg] = ef[i] + eb[i] + blin[tg];
  }
  __syncthreads();

  float tc[T] = {};
  float en = 0.f;
  float score = -1e30f;
  if (act) {
#pragma unroll
    for (int p = 0; p < T; p++) tc[p] = trans[p * T + tag];
    en = endv[tag];
    score = start[tag] + ev[tag];
  }

  float evn = ev[12 + tag];            // prefetch ev for t=1
  for (int t = 1; t < S; t++) {
    float evcur = evn;
    if (t + 1 < S) evn = ev[(t + 1) * 12 + tag];   // prefetch next (off dep path)
    float cand[T];
#pragma unroll
    for (int p = 0; p < T; p++) cand[p] = read_lane(score, p) + tc[p];
    float best = cand[0];
#pragma unroll
    for (int p = 1; p < T; p++) best = fmaxf(best, cand[p]);
    int bestp = T - 1;
#pragma unroll
    for (int p = T - 2; p >= 0; p--) bestp = (cand[p] == best) ? p : bestp;  // first max
    if (act) {
      score = best + evcur;
      bp[t * 16 + tag] = (unsigned char)bestp;
    }
  }
  if (act) score += en;
  __syncthreads();

  float cf[T];
#pragma unroll
  for (int p = 0; p < T; p++) cf[p] = read_lane(score, p);
  float bs = cf[0];
#pragma unroll
  for (int p = 1; p < T; p++) bs = fmaxf(bs, cf[p]);
  int last = T - 1;
#pragma unroll
  for (int p = T - 2; p >= 0; p--) last = (cf[p] == bs) ? p : last;

  if (lane == 0) {
    out[(size_t)B * S + b] = bs;
    int cur = last;
    out[(size_t)b * S + (S - 1)] = (float)cur;
    for (int t = S - 1; t >= 1; t--) {
      cur = bp[t * 16 + cur];
      out[(size_t)b * S + (t - 1)] = (float)cur;
    }
  }
}

// ---------------------------------------------------------------------------
extern "C" void kernel_launch(void* const* d_in, const int* in_sizes, int n_in,
                              void* d_out, int out_size, void* d_ws, size_t ws_size,
                              hipStream_t stream)
{
  const int*   x     = (const int*)d_in[0];
  const float* embed = (const float*)d_in[2];
  const float* Wih_f = (const float*)d_in[3];
  const float* Whh_f = (const float*)d_in[4];
  const float* b_f   = (const float*)d_in[5];
  const float* Wih_b = (const float*)d_in[6];
  const float* Whh_b = (const float*)d_in[7];
  const float* b_b   = (const float*)d_in[8];
  const float* Wlin  = (const float*)d_in[9];
  const float* blin  = (const float*)d_in[10];
  const float* start = (const float*)d_in[11];
  const float* trans = (const float*)d_in[12];
  const float* endv  = (const float*)d_in[13];
  float* out = (float*)d_out;

  char* ws = (char*)d_ws;
  float* Pf   = (float*)ws;  ws += (size_t)V * 400 * sizeof(float);
  float* Pb   = (float*)ws;  ws += (size_t)V * 400 * sizeof(float);
  float* emf  = (float*)ws;  ws += (size_t)B * S * T * sizeof(float);
  float* emb_ = (float*)ws;  ws += (size_t)B * S * T * sizeof(float);

  precompute_P<<<dim3(13, 235), 256, 0, stream>>>(embed, Wih_f, b_f, Wih_b, b_b, Pf, Pb);
  lstm_kernel<<<dim3(512), 512, 0, stream>>>(x, Pf, Pb, Whh_f, Whh_b, Wlin, emf, emb_);
  viterbi_kernel<<<dim3(256), 64, 0, stream>>>(emf, emb_, blin, start, trans, endv, out);
}